// Round 1
// 1322.112 us; speedup vs baseline: 1.1467x; 1.1467x over previous
//
#include <hip/hip_runtime.h>

// SparseLinear: y = x @ W^T + bias, W scattered from COO (sum duplicates).
// Strategy: scatter to dense W (fp32 atomics) -> bf16, then dense bf16 MFMA GEMM.
// GEMM: 256x256 tile, BK=64, 8 waves, 8-phase interleave with counted vmcnt
// (never 0 in main loop), XOR-swizzled LDS (conflict-free ds_read_b128),
// bijective XCD block swizzle, setprio around MFMA clusters.

#define M_DIM 65536
#define K_DIM 2048
#define N_DIM 2048
#define NNZ_CNT 262144

typedef short bf16x8 __attribute__((ext_vector_type(8)));
typedef float f32x4 __attribute__((ext_vector_type(4)));
typedef unsigned int u32x4 __attribute__((ext_vector_type(4)));

__device__ __forceinline__ unsigned short f2bf(float f) {
  union { float f; unsigned u; } v; v.f = f;
  unsigned r = v.u + 0x7fffu + ((v.u >> 16) & 1u);  // RNE
  return (unsigned short)(r >> 16);
}

__device__ __forceinline__ void glds16(const void* g, const void* l) {
  __builtin_amdgcn_global_load_lds(
      (const __attribute__((address_space(1))) void*)g,
      (__attribute__((address_space(3))) void*)l, 16, 0, 0);
}

__global__ void scatter_kernel(float* __restrict__ W, const float* __restrict__ vals,
                               const int* __restrict__ rows, const int* __restrict__ cols) {
  int i = blockIdx.x * 256 + threadIdx.x;
  atomicAdd(&W[(size_t)rows[i] * K_DIM + cols[i]], vals[i]);
}

// fp32 -> bf16, 8 elements/thread. total elements must be multiple of 2048.
__global__ void cvt_kernel(const float* __restrict__ in, unsigned short* __restrict__ out) {
  size_t i = ((size_t)blockIdx.x * 256 + threadIdx.x) * 8;
  f32x4 a = *(const f32x4*)(in + i);
  f32x4 b = *(const f32x4*)(in + i + 4);
  u32x4 p;
  p.x = f2bf(a.x) | ((unsigned)f2bf(a.y) << 16);
  p.y = f2bf(a.z) | ((unsigned)f2bf(a.w) << 16);
  p.z = f2bf(b.x) | ((unsigned)f2bf(b.y) << 16);
  p.w = f2bf(b.z) | ((unsigned)f2bf(b.w) << 16);
  *(u32x4*)(out + i) = p;
}

// ---------------------------------------------------------------------------
// 256x256 8-phase GEMM. C[m,n] = sum_k A[m,k]*W[n,k] + bias[n], A/W bf16 [.,K].
// LDS: buf0 A[0,32K) B[32K,64K) | buf1 A[64K,96K) B[96K,128K) | scrap [128K,+1K)
// Tile t -> buf t&1. Per K-tile, 4 phases; ds_reads front-loaded into phases
// 1-3 so the buffer is free for staging from phase 4 on. Staging schedule
// (half-tiles h0=A.lo h1=A.hi h2=B.lo h3=B.hi, 2 glds16/thread each):
//   P1: t_odd h2   P2: t_odd h3   P3: -       P4: t_ev+2 h0,h1  vmcnt(4)
//   P5: t_ev+2 h2  P6: t_ev+2 h3  P7: -       P8: t_odd+2 h0,h1 vmcnt(4)
// vmcnt(4) leaves exactly the 4 just-issued loads in flight; all older ones
// (the tile about to be read) are complete. Barriers bracket each phase.
// ---------------------------------------------------------------------------

#define BARF() do { asm volatile("" ::: "memory"); __builtin_amdgcn_s_barrier(); \
                    asm volatile("" ::: "memory"); } while (0)
#define WAIT_LGKM0() asm volatile("s_waitcnt lgkmcnt(0)" ::: "memory")
#define WAIT_VM4()   asm volatile("s_waitcnt vmcnt(4)" ::: "memory")
#define PRIO1() __builtin_amdgcn_s_setprio(1)
#define PRIO0() __builtin_amdgcn_s_setprio(0)

__global__ __launch_bounds__(512, 2) void gemm256_kernel(
    const unsigned short* __restrict__ xb, const unsigned short* __restrict__ wb,
    const float* __restrict__ bias, float* __restrict__ out) {
  __shared__ __align__(16) unsigned char lds[131072 + 1024];
  const int tid = threadIdx.x;
  const int lane = tid & 63;
  const int wave = tid >> 6;   // 0..7
  const int wm = wave >> 2;    // 0..1 : wave owns rows [wm*128, +128)
  const int wn = wave & 3;     // 0..3 : wave owns cols [wn*64, +64)
  const int r = lane & 15;
  const int q = lane >> 4;

  // bijective XCD swizzle: 2048 blocks, 8 XCDs, 256/chunk; n-fastest in chunk.
  const int bid = blockIdx.x;
  const int v = (bid & 7) * 256 + (bid >> 3);
  const int m0 = (v >> 3) * 256;
  const int n0 = (v & 7) * 256;

  // staging geometry: thread t covers row (t>>3), 16B slot ((t&7)^(t>>3)) --
  // the inverse of the read-side XOR swizzle, so LDS stays write-linear.
  const int srow = wave * 8 + (lane >> 3);              // 0..63 (+64 for j=1)
  const int scb = ((lane & 7) ^ (lane >> 3)) << 3;      // element offset in row
  const unsigned short* Ab = xb + (size_t)(m0 + srow) * K_DIM + scb;
  const unsigned short* Bb = wb + (size_t)(n0 + srow) * K_DIM + scb;
  unsigned char* lw = lds + wave * 1024;

  // frag-read column byte offsets, XOR-swizzled by row&7 (== r&7 for all frags)
  const int swx = (r & 7) << 4;
  const int cb0 = (q << 4) ^ swx;          // k-slice 0 (cols 0..31)
  const int cb1 = (64 | (q << 4)) ^ swx;   // k-slice 1 (cols 32..63)

  f32x4 acc[8][4] = {};
  bf16x8 av[4][2];   // 4 m-frags x 2 k-slices (current m-half)
  bf16x8 bA[2][2];   // n-frags 0,1
  bf16x8 bB[2][2];   // n-frags 2,3

#define STAGE(kt, h, bufbyte) do {                                              \
    const unsigned short* g_ = (((h) & 2) ? Bb : Ab)                            \
        + (size_t)(((h) & 1) * 128) * K_DIM + (kt) * 64;                        \
    unsigned char* l_ = lw + (bufbyte) + ((h) & 2) * 16384 + ((h) & 1) * 16384; \
    glds16(g_, l_);                                                             \
    glds16(g_ + (size_t)64 * K_DIM, l_ + 8192);                                 \
  } while (0)
#define STAGE_DUMMY() do { glds16(Ab, lds + 131072); glds16(Ab, lds + 131072); } while (0)

#define LDA4(base, mh) do { _Pragma("unroll") for (int i_ = 0; i_ < 4; ++i_) {  \
    const int rb_ = (wm * 128 + (mh) * 64 + i_ * 16 + r) * 128;                 \
    av[i_][0] = *(const bf16x8*)(lds + (base) + rb_ + cb0);                     \
    av[i_][1] = *(const bf16x8*)(lds + (base) + rb_ + cb1); } } while (0)

#define LDB2(dst, base, nh) do { _Pragma("unroll") for (int i_ = 0; i_ < 2; ++i_) { \
    const int rb_ = (wn * 64 + (nh) * 32 + i_ * 16 + r) * 128;                  \
    dst[i_][0] = *(const bf16x8*)(lds + (base) + 32768 + rb_ + cb0);            \
    dst[i_][1] = *(const bf16x8*)(lds + (base) + 32768 + rb_ + cb1); } } while (0)

#define MQ(mh, bb, nh) do { _Pragma("unroll") for (int i_ = 0; i_ < 4; ++i_)    \
    _Pragma("unroll") for (int j_ = 0; j_ < 2; ++j_) {                          \
      acc[(mh)*4+i_][(nh)*2+j_] = __builtin_amdgcn_mfma_f32_16x16x32_bf16(      \
          av[i_][0], bb[j_][0], acc[(mh)*4+i_][(nh)*2+j_], 0, 0, 0);            \
      acc[(mh)*4+i_][(nh)*2+j_] = __builtin_amdgcn_mfma_f32_16x16x32_bf16(      \
          av[i_][1], bb[j_][1], acc[(mh)*4+i_][(nh)*2+j_], 0, 0, 0); } } while (0)

  // prologue: tile0 full + tile1 A-halves; wait all but the 4 youngest.
  STAGE(0, 0, 0); STAGE(0, 1, 0); STAGE(0, 2, 0); STAGE(0, 3, 0);
  STAGE(1, 0, 65536); STAGE(1, 1, 65536);
  WAIT_VM4();
  BARF();

  for (int it = 0; it < 16; ++it) {
    const int t1 = 2 * it + 1;        // odd tile of this iteration (buf1)
    const bool lastit = (it == 15);
    // ---- P1: even tile, quadrant m0-3 x n0-1 ----
    LDA4(0, 0); LDB2(bA, 0, 0);
    STAGE(t1, 2, 65536);
    BARF(); WAIT_LGKM0();
    PRIO1(); MQ(0, bA, 0); PRIO0();
    BARF();
    // ---- P2: m0-3 x n2-3 ----
    LDB2(bB, 0, 1);
    STAGE(t1, 3, 65536);
    BARF(); WAIT_LGKM0();
    PRIO1(); MQ(0, bB, 1); PRIO0();
    BARF();
    // ---- P3: m4-7 x n2-3 (buf0 fully read after this phase) ----
    LDA4(0, 1);
    BARF(); WAIT_LGKM0();
    PRIO1(); MQ(1, bB, 1); PRIO0();
    BARF();
    // ---- P4: m4-7 x n0-1 (regs only); stage next even tile A into buf0 ----
    if (!lastit) { STAGE(t1 + 1, 0, 0); STAGE(t1 + 1, 1, 0); }
    else { STAGE_DUMMY(); STAGE_DUMMY(); }
    BARF();
    PRIO1(); MQ(1, bA, 0); PRIO0();
    WAIT_VM4();   // odd tile (buf1) complete; only P4's 4 loads in flight
    BARF();
    // ---- P5: odd tile, m0-3 x n0-1 ----
    LDA4(65536, 0); LDB2(bA, 65536, 0);
    if (!lastit) STAGE(t1 + 1, 2, 0); else STAGE_DUMMY();
    BARF(); WAIT_LGKM0();
    PRIO1(); MQ(0, bA, 0); PRIO0();
    BARF();
    // ---- P6: m0-3 x n2-3 ----
    LDB2(bB, 65536, 1);
    if (!lastit) STAGE(t1 + 1, 3, 0); else STAGE_DUMMY();
    BARF(); WAIT_LGKM0();
    PRIO1(); MQ(0, bB, 1); PRIO0();
    BARF();
    // ---- P7: m4-7 x n2-3 (buf1 fully read after this phase) ----
    LDA4(65536, 1);
    BARF(); WAIT_LGKM0();
    PRIO1(); MQ(1, bB, 1); PRIO0();
    BARF();
    // ---- P8: m4-7 x n0-1; stage next odd tile A into buf1 ----
    if (!lastit) { STAGE(t1 + 2, 0, 65536); STAGE(t1 + 2, 1, 65536); }
    else { STAGE_DUMMY(); STAGE_DUMMY(); }
    BARF();
    PRIO1(); MQ(1, bA, 0); PRIO0();
    WAIT_VM4();   // next even tile (buf0) complete
    BARF();
  }

  // epilogue: D layout col = lane&15 (=r), row = q*4 + reg
#pragma unroll
  for (int ni = 0; ni < 4; ++ni) {
    const int n = n0 + wn * 64 + ni * 16 + r;
    const float bv = bias[n];
#pragma unroll
    for (int mi = 0; mi < 8; ++mi) {
      const size_t mb = (size_t)(m0 + wm * 128 + mi * 16 + q * 4) * N_DIM + n;
#pragma unroll
      for (int rg = 0; rg < 4; ++rg)
        out[mb + (size_t)rg * N_DIM] = acc[mi][ni][rg] + bv;
    }
  }
}

// ---------------------------------------------------------------------------
// Fallback (workspace too small for Xb): old 128x128 kernel, inline fp32->bf16.
// ---------------------------------------------------------------------------
__global__ __launch_bounds__(256) void gemm_fallback(
    const float* __restrict__ xf, const unsigned short* __restrict__ wb,
    const float* __restrict__ bias, float* __restrict__ out) {
  __shared__ __align__(16) unsigned short lsA[128 * 32];
  __shared__ __align__(16) unsigned short lsB[128 * 32];
  const int tid = threadIdx.x;
  const int lane = tid & 63;
  const int wave = tid >> 6;
  const int m0 = blockIdx.y * 128;
  const int n0 = blockIdx.x * 128;
  const int r = lane & 15;
  const int q = lane >> 4;
  const int wm = (wave & 1) * 64;
  const int wn = (wave >> 1) * 64;
  f32x4 acc[4][4] = {};
  const int srow = wave * 16 + (lane >> 2);
  const int scol = (lane & 3) * 8;

  for (int kt = 0; kt < K_DIM / 32; ++kt) {
    const int kb = kt * 32;
    {
      const int row = tid >> 1;
      const int ce = (tid & 1) * 16;
      const float* g = xf + (size_t)(m0 + row) * K_DIM + kb + ce;
      f32x4 f0 = ((const f32x4*)g)[0];
      f32x4 f1 = ((const f32x4*)g)[1];
      f32x4 f2 = ((const f32x4*)g)[2];
      f32x4 f3 = ((const f32x4*)g)[3];
      u32x4 p0, p1;
      p0.x = f2bf(f0.x) | ((unsigned)f2bf(f0.y) << 16);
      p0.y = f2bf(f0.z) | ((unsigned)f2bf(f0.w) << 16);
      p0.z = f2bf(f1.x) | ((unsigned)f2bf(f1.y) << 16);
      p0.w = f2bf(f1.z) | ((unsigned)f2bf(f1.w) << 16);
      p1.x = f2bf(f2.x) | ((unsigned)f2bf(f2.y) << 16);
      p1.y = f2bf(f2.z) | ((unsigned)f2bf(f2.w) << 16);
      p1.z = f2bf(f3.x) | ((unsigned)f2bf(f3.y) << 16);
      p1.w = f2bf(f3.z) | ((unsigned)f2bf(f3.w) << 16);
      *(u32x4*)(lsA + row * 32 + ce) = p0;
      *(u32x4*)(lsA + row * 32 + ce + 8) = p1;
    }
#pragma unroll
    for (int i = 0; i < 2; ++i) {
      const unsigned short* g =
          wb + (size_t)(n0 + i * 64 + srow) * K_DIM + kb + scol;
      glds16(g, lsB + i * 2048 + wave * 512);
    }
    __syncthreads();
    bf16x8 af[4], bfr[4];
#pragma unroll
    for (int mi = 0; mi < 4; ++mi)
      af[mi] = *(const bf16x8*)(lsA + (wm + mi * 16 + r) * 32 + q * 8);
#pragma unroll
    for (int ni = 0; ni < 4; ++ni)
      bfr[ni] = *(const bf16x8*)(lsB + (wn + ni * 16 + r) * 32 + q * 8);
#pragma unroll
    for (int mi = 0; mi < 4; ++mi)
#pragma unroll
      for (int ni = 0; ni < 4; ++ni)
        acc[mi][ni] = __builtin_amdgcn_mfma_f32_16x16x32_bf16(
            af[mi], bfr[ni], acc[mi][ni], 0, 0, 0);
    __syncthreads();
  }
#pragma unroll
  for (int ni = 0; ni < 4; ++ni) {
    const int n = n0 + wn + ni * 16 + r;
    const float bv = bias[n];
#pragma unroll
    for (int mi = 0; mi < 4; ++mi) {
      const int mbase = m0 + wm + mi * 16 + q * 4;
#pragma unroll
      for (int reg = 0; reg < 4; ++reg)
        out[(size_t)(mbase + reg) * N_DIM + n] = acc[mi][ni][reg] + bv;
    }
  }
}

extern "C" void kernel_launch(void* const* d_in, const int* in_sizes, int n_in,
                              void* d_out, int out_size, void* d_ws, size_t ws_size,
                              hipStream_t stream) {
  const float* x = (const float*)d_in[0];
  const float* values = (const float*)d_in[1];
  const float* bias = (const float*)d_in[2];
  const int* rows = (const int*)d_in[3];
  const int* cols = (const int*)d_in[4];
  float* out = (float*)d_out;

  unsigned char* ws = (unsigned char*)d_ws;
  float* Wf = (float*)ws;                                    // 16 MB fp32 W
  unsigned short* Wb = (unsigned short*)(ws + (16u << 20));  // 8 MB bf16 W [N,K]
  unsigned short* Xb = (unsigned short*)(ws + (24u << 20));  // 256 MB bf16 x

  hipMemsetAsync(Wf, 0, (size_t)N_DIM * K_DIM * sizeof(float), stream);
  scatter_kernel<<<NNZ_CNT / 256, 256, 0, stream>>>(Wf, values, rows, cols);
  cvt_kernel<<<(N_DIM * K_DIM) / 2048, 256, 0, stream>>>(Wf, Wb);

  const size_t need = (24u << 20) + (size_t)M_DIM * K_DIM * 2;
  if (ws_size >= need) {
    cvt_kernel<<<((size_t)M_DIM * K_DIM) / 2048, 256, 0, stream>>>(x, Xb);
    gemm256_kernel<<<(M_DIM / 256) * (N_DIM / 256), 512, 0, stream>>>(Xb, Wb, bias, out);
  } else {
    dim3 grid(N_DIM / 128, M_DIM / 128);
    gemm_fallback<<<grid, 256, 0, stream>>>(x, Wb, bias, out);
  }
}